// Round 2
// baseline (541.662 us; speedup 1.0000x reference)
//
#include <hip/hip_runtime.h>
#include <hip/hip_bf16.h>
#include <cstdint>

#define DI __device__ __forceinline__

typedef __attribute__((ext_vector_type(8))) short bf16x8;   // 8 bf16 (4 VGPR) MFMA A/B frag
typedef __attribute__((ext_vector_type(4))) short s16x4;
typedef __attribute__((ext_vector_type(4))) float f32x4;    // MFMA C/D frag

static constexpr int BATCH = 8, SEQ = 2048;
static constexpr int ROWS = BATCH * SEQ;    // 16384
// logits = (q.k) * sqrt(512); fold sqrt(512)*log2(e) into Wq so we can use exp2
static constexpr float SCALE_Q = (float)(22.627416997969522 * 1.4426950408889634);

DI short f2bf(float f) { __hip_bfloat16 h = __float2bfloat16(f); return *reinterpret_cast<short*>(&h); }
DI float bf2f(short s) { __hip_bfloat16 h; *reinterpret_cast<short*>(&h) = s; return __bfloat162float(h); }

DI void gload_lds16(const void* gp, void* lp) {
  __builtin_amdgcn_global_load_lds(
      (__attribute__((address_space(1))) void*)const_cast<void*>(gp),
      (__attribute__((address_space(3))) void*)lp, 16, 0, 0);
}
DI f32x4 mfma16(bf16x8 a, bf16x8 b, f32x4 c) {
  return __builtin_amdgcn_mfma_f32_16x16x32_bf16(a, b, c, 0, 0, 0);
}

// ---------------------------------------------------------------------------
// prep: W [512k][512n] fp32 -> W^T [n][k] bf16 (hi/lo split for Wq,Wk; Wq scaled)
// grid: 4 mats * 64 tiles of 64x64
__global__ __launch_bounds__(256)
void prep_w(const float* __restrict__ Wq, const float* __restrict__ Wk,
            const float* __restrict__ Wv, const float* __restrict__ Wo,
            short* __restrict__ Wqk_hi, short* __restrict__ Wqk_lo,
            short* __restrict__ Wv_t, short* __restrict__ Wo_t)
{
  __shared__ float t[64][65];
  const int blk = blockIdx.x;
  const int mat = blk >> 6;
  const int tile = blk & 63;
  const int tn = (tile & 7) * 64;
  const int tk = (tile >> 3) * 64;
  const float* src = mat == 0 ? Wq : mat == 1 ? Wk : mat == 2 ? Wv : Wo;
  const float scale = (mat == 0) ? SCALE_Q : 1.0f;
  const int tid = threadIdx.x;
#pragma unroll
  for (int i = 0; i < 16; ++i) {
    int idx = i * 256 + tid;
    t[idx >> 6][idx & 63] = src[(size_t)(tk + (idx >> 6)) * 512 + tn + (idx & 63)];
  }
  __syncthreads();
#pragma unroll
  for (int i = 0; i < 16; ++i) {
    int idx = i * 256 + tid;
    int nn = idx >> 6, kk = idx & 63;
    float v = t[kk][nn] * scale;
    short hb = f2bf(v);
    size_t o = (size_t)(tn + nn) * 512 + (tk + kk);
    if (mat <= 1) {
      Wqk_hi[(size_t)mat * 512 * 512 + o] = hb;
      Wqk_lo[(size_t)mat * 512 * 512 + o] = f2bf(v - bf2f(hb));
    } else if (mat == 2) Wv_t[o] = hb;
    else Wo_t[o] = hb;
  }
}

// ---------------------------------------------------------------------------
// GEMM: C[16384 x N] = A[16384 x 512] * B^T[N x 512]
// MODE 0: A = x fp32 (split hi/lo), B split, N=1024 -> Q(hi/lo), K(hi/lo) as [bh][m][d]
// MODE 1: A = x fp32 (hi only),     B single, N=512 -> V^T as [bh][d][m]
// MODE 2: A = O bf16,               B single, N=512 -> out fp32 + bias
// 128x128 tile, BK=32, 4 waves (2x2), 16x16x32 bf16 MFMA. Linear LDS (64B rows).
template<int MODE>
__global__ __launch_bounds__(256, 2)
void gemm_kern(const float* __restrict__ Axf, const short* __restrict__ Axb,
               const short* __restrict__ Bhg, const short* __restrict__ Blg,
               short* __restrict__ O0h, short* __restrict__ O0l,
               short* __restrict__ O1h, short* __restrict__ O1l,
               float* __restrict__ Of, const float* __restrict__ bias)
{
  constexpr bool SPLIT = (MODE == 0);
  __shared__ __align__(16) short Ah[128 * 32];
  __shared__ __align__(16) short Bh[128 * 32];
  __shared__ __align__(16) short Al[SPLIT ? 128 * 32 : 16];
  __shared__ __align__(16) short Bl[SPLIT ? 128 * 32 : 16];

  const int tid = threadIdx.x;
  const int wave = tid >> 6, lane = tid & 63, lo = lane & 15, hi4 = lane >> 4;
  const int wr = wave >> 1, wc = wave & 1;
  const int m0 = blockIdx.y * 128, n0 = blockIdx.x * 128;

  f32x4 acc[4][4] = {};

  for (int kt = 0; kt < 16; ++kt) {
    __syncthreads();   // previous iteration's LDS reads complete
    // ---- stage A (linear: row*64B + chunk16B, chunk c holds k = c*8..c*8+7)
    if constexpr (MODE != 2) {
#pragma unroll
      for (int r2 = 0; r2 < 4; ++r2) {
        int idx = r2 * 256 + tid;
        int row = idx >> 3, c4 = idx & 7;
        const float4 v = *reinterpret_cast<const float4*>(Axf + (size_t)(m0 + row) * 512 + kt * 32 + c4 * 4);
        s16x4 h4, l4;
#pragma unroll
        for (int j = 0; j < 4; ++j) {
          float f = ((const float*)&v)[j];
          short hb = f2bf(f);
          h4[j] = hb;
          if constexpr (SPLIT) l4[j] = f2bf(f - bf2f(hb));
        }
        int off = row * 64 + c4 * 8;
        *reinterpret_cast<s16x4*>((char*)Ah + off) = h4;
        if constexpr (SPLIT) *reinterpret_cast<s16x4*>((char*)Al + off) = l4;
      }
    } else {
#pragma unroll
      for (int is = 0; is < 2; ++is) {
        int rowl = is * 64 + wave * 16 + (lane >> 2);
        const char* src = (const char*)Axb + ((size_t)(m0 + rowl) * 512 + kt * 32) * 2 + (lane & 3) * 16;
        gload_lds16(src, (char*)Ah + is * 4096 + wave * 1024);
      }
    }
    // ---- stage B (global_load_lds, linear)
#pragma unroll
    for (int is = 0; is < 2; ++is) {
      int rowl = is * 64 + wave * 16 + (lane >> 2);
      size_t gb = ((size_t)(n0 + rowl) * 512 + kt * 32) * 2 + (lane & 3) * 16;
      gload_lds16((const char*)Bhg + gb, (char*)Bh + is * 4096 + wave * 1024);
      if constexpr (SPLIT)
        gload_lds16((const char*)Blg + gb, (char*)Bl + is * 4096 + wave * 1024);
    }
    __syncthreads();
    // ---- fragments (A row = lane&15, k = (lane>>4)*8 + j; B likewise from B^T rows)
    bf16x8 a_h[4], a_l[4], b_h[4], b_l[4];
#pragma unroll
    for (int m = 0; m < 4; ++m) {
      int off = (wr * 64 + m * 16 + lo) * 64 + hi4 * 16;
      a_h[m] = *reinterpret_cast<const bf16x8*>((const char*)Ah + off);
      if constexpr (SPLIT) a_l[m] = *reinterpret_cast<const bf16x8*>((const char*)Al + off);
    }
#pragma unroll
    for (int n = 0; n < 4; ++n) {
      int off = (wc * 64 + n * 16 + lo) * 64 + hi4 * 16;
      b_h[n] = *reinterpret_cast<const bf16x8*>((const char*)Bh + off);
      if constexpr (SPLIT) b_l[n] = *reinterpret_cast<const bf16x8*>((const char*)Bl + off);
    }
#pragma unroll
    for (int m = 0; m < 4; ++m)
#pragma unroll
      for (int n = 0; n < 4; ++n) {
        acc[m][n] = mfma16(a_h[m], b_h[n], acc[m][n]);
        if constexpr (SPLIT) {
          acc[m][n] = mfma16(a_h[m], b_l[n], acc[m][n]);
          acc[m][n] = mfma16(a_l[m], b_h[n], acc[m][n]);
        }
      }
  }
  // ---- epilogue. D layout: col = lane&15, row = (lane>>4)*4 + j
#pragma unroll
  for (int m = 0; m < 4; ++m)
#pragma unroll
    for (int n = 0; n < 4; ++n) {
      if constexpr (MODE == 1) {
        // pack 4 consecutive m into one 8B store of V^T[bh][d][m]
        int cg = n0 + wc * 64 + n * 16 + lo;          // 0..511 = h*64+d
        int rgb = m0 + wr * 64 + m * 16 + hi4 * 4;    // j = 0..3 consecutive rows
        int bh = (rgb >> 11) * 8 + (cg >> 6);
        s16x4 vt4;
#pragma unroll
        for (int j = 0; j < 4; ++j) vt4[j] = f2bf(acc[m][n][j]);
        size_t o = ((size_t)(bh * 64 + (cg & 63))) * 2048 + (rgb & 2047);
        *reinterpret_cast<s16x4*>(O0h + o) = vt4;
      } else {
#pragma unroll
        for (int j = 0; j < 4; ++j) {
          int rg = m0 + wr * 64 + m * 16 + hi4 * 4 + j;
          int cg = n0 + wc * 64 + n * 16 + lo;
          float v = acc[m][n][j];
          if constexpr (MODE == 2) {
            Of[(size_t)rg * 512 + cg] = v + bias[cg];
          } else {
            int mat = cg >> 9;      // uniform per block
            int c9 = cg & 511;
            size_t o = ((size_t)((rg >> 11) * 8 + (c9 >> 6)) * 2048 + (rg & 2047)) * 64 + (c9 & 63);
            short hb = f2bf(v);
            short lb = f2bf(v - bf2f(hb));
            if (mat == 0) { O0h[o] = hb; O0l[o] = lb; }
            else          { O1h[o] = hb; O1l[o] = lb; }
          }
        }
      }
    }
}

// ---------------------------------------------------------------------------
// Flash attention. grid = (32 q-tiles, 64 bh). 4 waves x 16 q-rows, 64-key tiles.
// Q,K in bf16 hi/lo (3-product MFMA for S); V^T [bh][d][m] plain bf16.
// All LDS linear (128B rows). P buffer per-wave.
__global__ __launch_bounds__(256, 2)
void attn_kern(const short* __restrict__ Qh, const short* __restrict__ Ql,
               const short* __restrict__ Kh, const short* __restrict__ Kl,
               const short* __restrict__ VTg, short* __restrict__ Og)
{
  __shared__ __align__(16) short Ksh[64 * 64];
  __shared__ __align__(16) short Ksl[64 * 64];
  __shared__ __align__(16) short Vts[64 * 64];
  __shared__ __align__(16) short Ps[4][1024];

  const int bh = blockIdx.y, qt = blockIdx.x;
  const int tid = threadIdx.x, wave = tid >> 6, lane = tid & 63, lo = lane & 15, hi4 = lane >> 4;
  const int q0 = qt * 64;

  // Q fragments (A-operand: row = lane&15, k = (lane>>4)*8 + j per 32-k MFMA)
  const size_t qoff = ((size_t)bh * 2048 + q0 + wave * 16 + lo) * 64;
  bf16x8 qh[2], ql[2];
#pragma unroll
  for (int kk = 0; kk < 2; ++kk) {
    qh[kk] = *reinterpret_cast<const bf16x8*>(Qh + qoff + kk * 32 + hi4 * 8);
    ql[kk] = *reinterpret_cast<const bf16x8*>(Ql + qoff + kk * 32 + hi4 * 8);
  }

  f32x4 acc_o[4] = {};
  float m_run[4], l_run[4];
#pragma unroll
  for (int j = 0; j < 4; ++j) { m_run[j] = -3.0e38f; l_run[j] = 0.f; }

  short* pw = &Ps[wave][0];

  for (int kt = 0; kt < 32; ++kt) {
    __syncthreads();   // all waves done reading previous K/V tile
    // ---- stage K hi/lo rows [64 key][64 d] + V^T rows [64 d][64 key], linear
#pragma unroll
    for (int is = 0; is < 2; ++is) {
      int rowl = is * 32 + wave * 8 + (lane >> 3);
      int chunk = lane & 7;
      size_t gbK = ((size_t)bh * 2048 + kt * 64 + rowl) * 128 + chunk * 16;   // bytes
      gload_lds16((const char*)Kh + gbK, (char*)Ksh + is * 4096 + wave * 1024);
      gload_lds16((const char*)Kl + gbK, (char*)Ksl + is * 4096 + wave * 1024);
      size_t gbV = (((size_t)bh * 64 + rowl) * 2048 + kt * 64) * 2 + chunk * 16;  // bytes
      gload_lds16((const char*)VTg + gbV, (char*)Vts + is * 4096 + wave * 1024);
    }
    __syncthreads();

    // ---- S = Q'K^T (hh + hl + lh), 4 key-blocks of 16
    f32x4 s[4];
#pragma unroll
    for (int kb = 0; kb < 4; ++kb) {
      f32x4 t = {0.f, 0.f, 0.f, 0.f};
#pragma unroll
      for (int kk = 0; kk < 2; ++kk) {
        int off = (kb * 16 + lo) * 128 + kk * 64 + hi4 * 16;
        bf16x8 kh8 = *reinterpret_cast<const bf16x8*>((const char*)Ksh + off);
        bf16x8 kl8 = *reinterpret_cast<const bf16x8*>((const char*)Ksl + off);
        t = mfma16(qh[kk], kh8, t);
        t = mfma16(qh[kk], kl8, t);
        t = mfma16(ql[kk], kh8, t);
      }
      s[kb] = t;
    }

    // ---- online softmax (rows = hi4*4+j, cols spread across the 16 lo-lanes)
    float mt[4];
#pragma unroll
    for (int j = 0; j < 4; ++j)
      mt[j] = fmaxf(fmaxf(s[0][j], s[1][j]), fmaxf(s[2][j], s[3][j]));
#pragma unroll
    for (int d = 1; d <= 8; d <<= 1) {
#pragma unroll
      for (int j = 0; j < 4; ++j) mt[j] = fmaxf(mt[j], __shfl_xor(mt[j], d));
    }
    float corr[4], ls[4];
#pragma unroll
    for (int j = 0; j < 4; ++j) {
      float mn = fmaxf(m_run[j], mt[j]);
      corr[j] = exp2f(m_run[j] - mn);
      m_run[j] = mn;
      ls[j] = 0.f;
    }
#pragma unroll
    for (int kb = 0; kb < 4; ++kb)
#pragma unroll
      for (int j = 0; j < 4; ++j) {
        float p = exp2f(s[kb][j] - m_run[j]);
        s[kb][j] = p;
        ls[j] += p;
      }
#pragma unroll
    for (int d = 1; d <= 8; d <<= 1) {
#pragma unroll
      for (int j = 0; j < 4; ++j) ls[j] += __shfl_xor(ls[j], d);
    }
#pragma unroll
    for (int j = 0; j < 4; ++j) l_run[j] = l_run[j] * corr[j] + ls[j];
#pragma unroll
    for (int db = 0; db < 4; ++db)
#pragma unroll
      for (int j = 0; j < 4; ++j) acc_o[db][j] *= corr[j];

    // ---- P -> LDS (per-wave, linear 128B rows); re-read as A-operand fragments
#pragma unroll
    for (int kb = 0; kb < 4; ++kb)
#pragma unroll
      for (int j = 0; j < 4; ++j) {
        int row = hi4 * 4 + j, col = kb * 16 + lo;
        *reinterpret_cast<short*>((char*)pw + row * 128 + col * 2) = f2bf(s[kb][j]);
      }
    __builtin_amdgcn_sched_barrier(0);   // keep P writes before P reads
    bf16x8 pa[2];
#pragma unroll
    for (int kk = 0; kk < 2; ++kk)
      pa[kk] = *reinterpret_cast<const bf16x8*>((const char*)pw + lo * 128 + kk * 64 + hi4 * 16);

    // ---- PV: B-operand = rows of V^T tile (same pattern as K reads)
#pragma unroll
    for (int db = 0; db < 4; ++db) {
#pragma unroll
      for (int kk = 0; kk < 2; ++kk) {
        int voff = (db * 16 + lo) * 128 + kk * 64 + hi4 * 16;
        bf16x8 v8 = *reinterpret_cast<const bf16x8*>((const char*)Vts + voff);
        acc_o[db] = mfma16(pa[kk], v8, acc_o[db]);
      }
    }
  }

  // ---- epilogue: O[b, m, h*64 + d] bf16
  const int b = bh >> 3, h = bh & 7;
#pragma unroll
  for (int j = 0; j < 4; ++j) {
    float inv = 1.0f / l_run[j];
    int mrow = q0 + wave * 16 + hi4 * 4 + j;
    size_t base = ((size_t)(b * 2048 + mrow)) * 512 + h * 64;
#pragma unroll
    for (int db = 0; db < 4; ++db)
      Og[base + db * 16 + lo] = f2bf(acc_o[db][j] * inv);
  }
}

// ---------------------------------------------------------------------------
extern "C" void kernel_launch(void* const* d_in, const int* in_sizes, int n_in,
                              void* d_out, int out_size, void* d_ws, size_t ws_size,
                              hipStream_t stream) {
  const float* x  = (const float*)d_in[0];
  const float* Wq = (const float*)d_in[1];
  const float* Wk = (const float*)d_in[2];
  const float* Wv = (const float*)d_in[3];
  const float* Wo = (const float*)d_in[4];
  const float* bo = (const float*)d_in[5];
  float* out = (float*)d_out;

  char* ws = (char*)d_ws;
  short* Wqk_hi = (short*)(ws);                           // [1024][512]
  short* Wqk_lo = (short*)(ws + (1 << 20));
  short* Wv_t   = (short*)(ws + (2 << 20));               // [512][512]
  short* Wo_t   = (short*)(ws + (2 << 20) + 512 * 512 * 2);
  char* big = ws + 3 * (1 << 20);
  const size_t SZ = (size_t)ROWS * 512 * 2;               // 16 MiB per tensor
  short* Qh = (short*)(big);
  short* Ql = (short*)(big + SZ);
  short* Kh = (short*)(big + 2 * SZ);
  short* Kl = (short*)(big + 3 * SZ);
  short* VT = (short*)(big + 4 * SZ);                     // [bh][d][m]
  short* Ob = (short*)(big + 5 * SZ);
  (void)in_sizes; (void)n_in; (void)out_size; (void)ws_size;

  prep_w<<<dim3(256), dim3(256), 0, stream>>>(Wq, Wk, Wv, Wo, Wqk_hi, Wqk_lo, Wv_t, Wo_t);
  gemm_kern<0><<<dim3(8, 128), dim3(256), 0, stream>>>(x, nullptr, Wqk_hi, Wqk_lo,
                                                       Qh, Ql, Kh, Kl, nullptr, nullptr);
  gemm_kern<1><<<dim3(4, 128), dim3(256), 0, stream>>>(x, nullptr, Wv_t, nullptr,
                                                       VT, nullptr, nullptr, nullptr, nullptr, nullptr);
  attn_kern<<<dim3(32, 64), dim3(256), 0, stream>>>(Qh, Ql, Kh, Kl, VT, Ob);
  gemm_kern<2><<<dim3(4, 128), dim3(256), 0, stream>>>(nullptr, Ob, Wo_t, nullptr,
                                                       nullptr, nullptr, nullptr, nullptr, out, bo);
}

// Round 3
// 463.895 us; speedup vs baseline: 1.1676x; 1.1676x over previous
//
#include <hip/hip_runtime.h>
#include <hip/hip_bf16.h>
#include <cstdint>

#define DI __device__ __forceinline__

typedef __attribute__((ext_vector_type(8))) short bf16x8;   // 8 bf16 (4 VGPR) MFMA A/B frag
typedef __attribute__((ext_vector_type(4))) short s16x4;
typedef __attribute__((ext_vector_type(4))) float f32x4;    // MFMA C/D frag

static constexpr int BATCH = 8, SEQ = 2048;
static constexpr int ROWS = BATCH * SEQ;    // 16384
// logits = (q.k) * sqrt(512); fold sqrt(512)*log2(e) into Wq so we can use exp2
static constexpr float SCALE_Q = (float)(22.627416997969522 * 1.4426950408889634);

DI short f2bf(float f) { __hip_bfloat16 h = __float2bfloat16(f); return *reinterpret_cast<short*>(&h); }
DI float bf2f(short s) { __hip_bfloat16 h; *reinterpret_cast<short*>(&h) = s; return __bfloat162float(h); }

DI void gload_lds16(const void* gp, void* lp) {
  __builtin_amdgcn_global_load_lds(
      (__attribute__((address_space(1))) void*)const_cast<void*>(gp),
      (__attribute__((address_space(3))) void*)lp, 16, 0, 0);
}
DI f32x4 mfma16(bf16x8 a, bf16x8 b, f32x4 c) {
  return __builtin_amdgcn_mfma_f32_16x16x32_bf16(a, b, c, 0, 0, 0);
}

// ---------------------------------------------------------------------------
// prep: W [512k][512n] fp32 -> W^T [n][k] bf16 (hi/lo split for Wq,Wk; Wq scaled)
// grid: 4 mats * 64 tiles of 64x64
__global__ __launch_bounds__(256)
void prep_w(const float* __restrict__ Wq, const float* __restrict__ Wk,
            const float* __restrict__ Wv, const float* __restrict__ Wo,
            short* __restrict__ Wqk_hi, short* __restrict__ Wqk_lo,
            short* __restrict__ Wv_t, short* __restrict__ Wo_t)
{
  __shared__ float t[64][65];
  const int blk = blockIdx.x;
  const int mat = blk >> 6;
  const int tile = blk & 63;
  const int tn = (tile & 7) * 64;
  const int tk = (tile >> 3) * 64;
  const float* src = mat == 0 ? Wq : mat == 1 ? Wk : mat == 2 ? Wv : Wo;
  const float scale = (mat == 0) ? SCALE_Q : 1.0f;
  const int tid = threadIdx.x;
#pragma unroll
  for (int i = 0; i < 16; ++i) {
    int idx = i * 256 + tid;
    t[idx >> 6][idx & 63] = src[(size_t)(tk + (idx >> 6)) * 512 + tn + (idx & 63)];
  }
  __syncthreads();
#pragma unroll
  for (int i = 0; i < 16; ++i) {
    int idx = i * 256 + tid;
    int nn = idx >> 6, kk = idx & 63;
    float v = t[kk][nn] * scale;
    short hb = f2bf(v);
    size_t o = (size_t)(tn + nn) * 512 + (tk + kk);
    if (mat <= 1) {
      Wqk_hi[(size_t)mat * 512 * 512 + o] = hb;
      Wqk_lo[(size_t)mat * 512 * 512 + o] = f2bf(v - bf2f(hb));
    } else if (mat == 2) Wv_t[o] = hb;
    else Wo_t[o] = hb;
  }
}

// ---------------------------------------------------------------------------
// GEMM: C[16384 x N] = A[16384 x 512] * B^T[N x 512]
// MODE 0: A = x fp32 (split hi/lo), B split, N=1024 -> Q(hi/lo), K(hi/lo) as [bh][m][d]
// MODE 1: A = x fp32 (hi only),     B single, N=512 -> V^T as [bh][d][m]
// MODE 2: A = O bf16,               B single, N=512 -> out fp32 + bias
// 128x128 tile, BK=32, 4 waves (2x2), 16x16x32 bf16 MFMA.
// LDS rows are 64B = 4 chunks of 16B; chunk XOR-swizzled with ((row>>1)&3)
// (write-side permute == read-side permute, bijective) -> frag reads 2-way (free).
template<int MODE>
__global__ __launch_bounds__(256, 2)
void gemm_kern(const float* __restrict__ Axf, const short* __restrict__ Axb,
               const short* __restrict__ Bhg, const short* __restrict__ Blg,
               short* __restrict__ O0h, short* __restrict__ O0l,
               short* __restrict__ O1h, short* __restrict__ O1l,
               float* __restrict__ Of, const float* __restrict__ bias)
{
  constexpr bool SPLIT = (MODE == 0);
  __shared__ __align__(16) short Ah[128 * 32];
  __shared__ __align__(16) short Bh[128 * 32];
  __shared__ __align__(16) short Al[SPLIT ? 128 * 32 : 16];
  __shared__ __align__(16) short Bl[SPLIT ? 128 * 32 : 16];

  const int tid = threadIdx.x;
  const int wave = tid >> 6, lane = tid & 63, lo = lane & 15, hi4 = lane >> 4;
  const int wr = wave >> 1, wc = wave & 1;
  const int m0 = blockIdx.y * 128, n0 = blockIdx.x * 128;

  f32x4 acc[4][4] = {};

  for (int kt = 0; kt < 16; ++kt) {
    __syncthreads();   // previous iteration's LDS reads complete
    // ---- stage A (rows 64B; chunk c holds k = c*8..c*8+7, stored at chunk c^((row>>1)&3))
    if constexpr (MODE != 2) {
#pragma unroll
      for (int r2 = 0; r2 < 4; ++r2) {
        int idx = r2 * 256 + tid;
        int row = idx >> 3, c4 = idx & 7;
        const float4 v = *reinterpret_cast<const float4*>(Axf + (size_t)(m0 + row) * 512 + kt * 32 + c4 * 4);
        s16x4 h4, l4;
#pragma unroll
        for (int j = 0; j < 4; ++j) {
          float f = ((const float*)&v)[j];
          short hb = f2bf(f);
          h4[j] = hb;
          if constexpr (SPLIT) l4[j] = f2bf(f - bf2f(hb));
        }
        int off = row * 64 + ((((c4 >> 1) ^ ((row >> 1) & 3)) << 4) | ((c4 & 1) << 3));
        *reinterpret_cast<s16x4*>((char*)Ah + off) = h4;
        if constexpr (SPLIT) *reinterpret_cast<s16x4*>((char*)Al + off) = l4;
      }
    } else {
#pragma unroll
      for (int is = 0; is < 2; ++is) {
        int rowl = is * 64 + wave * 16 + (lane >> 2);
        int chunk = (lane & 3) ^ ((rowl >> 1) & 3);
        const char* src = (const char*)Axb + ((size_t)(m0 + rowl) * 512 + kt * 32) * 2 + chunk * 16;
        gload_lds16(src, (char*)Ah + is * 4096 + wave * 1024);
      }
    }
    // ---- stage B (global_load_lds; source chunk permuted so LDS lands swizzled)
#pragma unroll
    for (int is = 0; is < 2; ++is) {
      int rowl = is * 64 + wave * 16 + (lane >> 2);
      int chunk = (lane & 3) ^ ((rowl >> 1) & 3);
      size_t gb = ((size_t)(n0 + rowl) * 512 + kt * 32) * 2 + chunk * 16;
      gload_lds16((const char*)Bhg + gb, (char*)Bh + is * 4096 + wave * 1024);
      if constexpr (SPLIT)
        gload_lds16((const char*)Blg + gb, (char*)Bl + is * 4096 + wave * 1024);
    }
    __syncthreads();
    // ---- fragments (A row = lane&15, k-chunk hi4 read at slot hi4^((row>>1)&3))
    bf16x8 a_h[4], a_l[4], b_h[4], b_l[4];
#pragma unroll
    for (int m = 0; m < 4; ++m) {
      int ar = wr * 64 + m * 16 + lo;
      int off = ar * 64 + ((hi4 ^ ((ar >> 1) & 3)) << 4);
      a_h[m] = *reinterpret_cast<const bf16x8*>((const char*)Ah + off);
      if constexpr (SPLIT) a_l[m] = *reinterpret_cast<const bf16x8*>((const char*)Al + off);
    }
#pragma unroll
    for (int n = 0; n < 4; ++n) {
      int br = wc * 64 + n * 16 + lo;
      int off = br * 64 + ((hi4 ^ ((br >> 1) & 3)) << 4);
      b_h[n] = *reinterpret_cast<const bf16x8*>((const char*)Bh + off);
      if constexpr (SPLIT) b_l[n] = *reinterpret_cast<const bf16x8*>((const char*)Bl + off);
    }
#pragma unroll
    for (int m = 0; m < 4; ++m)
#pragma unroll
      for (int n = 0; n < 4; ++n) {
        acc[m][n] = mfma16(a_h[m], b_h[n], acc[m][n]);
        if constexpr (SPLIT) {
          acc[m][n] = mfma16(a_h[m], b_l[n], acc[m][n]);
          acc[m][n] = mfma16(a_l[m], b_h[n], acc[m][n]);
        }
      }
  }
  // ---- epilogue. D layout: col = lane&15, row = (lane>>4)*4 + j
#pragma unroll
  for (int m = 0; m < 4; ++m)
#pragma unroll
    for (int n = 0; n < 4; ++n) {
      if constexpr (MODE == 1) {
        // pack 4 consecutive m into one 8B store of V^T[bh][d][m]
        int cg = n0 + wc * 64 + n * 16 + lo;          // 0..511 = h*64+d
        int rgb = m0 + wr * 64 + m * 16 + hi4 * 4;    // j = 0..3 consecutive rows
        int bh = (rgb >> 11) * 8 + (cg >> 6);
        s16x4 vt4;
#pragma unroll
        for (int j = 0; j < 4; ++j) vt4[j] = f2bf(acc[m][n][j]);
        size_t o = ((size_t)(bh * 64 + (cg & 63))) * 2048 + (rgb & 2047);
        *reinterpret_cast<s16x4*>(O0h + o) = vt4;
      } else {
#pragma unroll
        for (int j = 0; j < 4; ++j) {
          int rg = m0 + wr * 64 + m * 16 + hi4 * 4 + j;
          int cg = n0 + wc * 64 + n * 16 + lo;
          float v = acc[m][n][j];
          if constexpr (MODE == 2) {
            Of[(size_t)rg * 512 + cg] = v + bias[cg];
          } else {
            int mat = cg >> 9;      // uniform per block
            int c9 = cg & 511;
            size_t o = ((size_t)((rg >> 11) * 8 + (c9 >> 6)) * 2048 + (rg & 2047)) * 64 + (c9 & 63);
            short hb = f2bf(v);
            short lb = f2bf(v - bf2f(hb));
            if (mat == 0) { O0h[o] = hb; O0l[o] = lb; }
            else          { O1h[o] = hb; O1l[o] = lb; }
          }
        }
      }
    }
}

// ---------------------------------------------------------------------------
// Flash attention. grid = (32 q-tiles, 64 bh). 4 waves x 16 q-rows, 64-key tiles.
// Q,K in bf16 hi/lo (3-product MFMA for S); V^T [bh][d][m] plain bf16.
// LDS rows are 128B = 8 chunks of 16B, XOR-swizzled: slot s of row r holds
// chunk s^(r&7) (source-permuted on global_load_lds; same XOR on reads).
__global__ __launch_bounds__(256, 2)
void attn_kern(const short* __restrict__ Qh, const short* __restrict__ Ql,
               const short* __restrict__ Kh, const short* __restrict__ Kl,
               const short* __restrict__ VTg, short* __restrict__ Og)
{
  __shared__ __align__(16) short Ksh[64 * 64];
  __shared__ __align__(16) short Ksl[64 * 64];
  __shared__ __align__(16) short Vts[64 * 64];
  __shared__ __align__(16) short Ps[4][1024];

  const int bh = blockIdx.y, qt = blockIdx.x;
  const int tid = threadIdx.x, wave = tid >> 6, lane = tid & 63, lo = lane & 15, hi4 = lane >> 4;
  const int q0 = qt * 64;

  // Q fragments (A-operand: row = lane&15, k = (lane>>4)*8 + j per 32-k MFMA)
  const size_t qoff = ((size_t)bh * 2048 + q0 + wave * 16 + lo) * 64;
  bf16x8 qh[2], ql[2];
#pragma unroll
  for (int kk = 0; kk < 2; ++kk) {
    qh[kk] = *reinterpret_cast<const bf16x8*>(Qh + qoff + kk * 32 + hi4 * 8);
    ql[kk] = *reinterpret_cast<const bf16x8*>(Ql + qoff + kk * 32 + hi4 * 8);
  }

  f32x4 acc_o[4] = {};
  float m_run[4], l_run[4];
#pragma unroll
  for (int j = 0; j < 4; ++j) { m_run[j] = -3.0e38f; l_run[j] = 0.f; }

  short* pw = &Ps[wave][0];

  for (int kt = 0; kt < 32; ++kt) {
    __syncthreads();   // all waves done reading previous K/V tile
    // ---- stage K hi/lo rows [64 key][64 d] + V^T rows [64 d][64 key], swizzled src
#pragma unroll
    for (int is = 0; is < 2; ++is) {
      int rowl = is * 32 + wave * 8 + (lane >> 3);
      int chunk = (lane & 7) ^ (rowl & 7);
      size_t gbK = ((size_t)bh * 2048 + kt * 64 + rowl) * 128 + chunk * 16;   // bytes
      gload_lds16((const char*)Kh + gbK, (char*)Ksh + is * 4096 + wave * 1024);
      gload_lds16((const char*)Kl + gbK, (char*)Ksl + is * 4096 + wave * 1024);
      size_t gbV = (((size_t)bh * 64 + rowl) * 2048 + kt * 64) * 2 + chunk * 16;  // bytes
      gload_lds16((const char*)VTg + gbV, (char*)Vts + is * 4096 + wave * 1024);
    }
    __syncthreads();

    // ---- S = Q'K^T (hh + hl + lh), 4 key-blocks of 16
    f32x4 s[4];
#pragma unroll
    for (int kb = 0; kb < 4; ++kb) {
      f32x4 t = {0.f, 0.f, 0.f, 0.f};
#pragma unroll
      for (int kk = 0; kk < 2; ++kk) {
        int krow = kb * 16 + lo;
        int off = krow * 128 + ((kk * 64 + hi4 * 16) ^ ((krow & 7) << 4));
        bf16x8 kh8 = *reinterpret_cast<const bf16x8*>((const char*)Ksh + off);
        bf16x8 kl8 = *reinterpret_cast<const bf16x8*>((const char*)Ksl + off);
        t = mfma16(qh[kk], kh8, t);
        t = mfma16(qh[kk], kl8, t);
        t = mfma16(ql[kk], kh8, t);
      }
      s[kb] = t;
    }

    // ---- online softmax (rows = hi4*4+j, cols spread across the 16 lo-lanes)
    float mt[4];
#pragma unroll
    for (int j = 0; j < 4; ++j)
      mt[j] = fmaxf(fmaxf(s[0][j], s[1][j]), fmaxf(s[2][j], s[3][j]));
#pragma unroll
    for (int d = 1; d <= 8; d <<= 1) {
#pragma unroll
      for (int j = 0; j < 4; ++j) mt[j] = fmaxf(mt[j], __shfl_xor(mt[j], d));
    }
    float corr[4], ls[4];
#pragma unroll
    for (int j = 0; j < 4; ++j) {
      float mn = fmaxf(m_run[j], mt[j]);
      corr[j] = exp2f(m_run[j] - mn);
      m_run[j] = mn;
      ls[j] = 0.f;
    }
#pragma unroll
    for (int kb = 0; kb < 4; ++kb)
#pragma unroll
      for (int j = 0; j < 4; ++j) {
        float p = exp2f(s[kb][j] - m_run[j]);
        s[kb][j] = p;
        ls[j] += p;
      }
#pragma unroll
    for (int d = 1; d <= 8; d <<= 1) {
#pragma unroll
      for (int j = 0; j < 4; ++j) ls[j] += __shfl_xor(ls[j], d);
    }
#pragma unroll
    for (int j = 0; j < 4; ++j) l_run[j] = l_run[j] * corr[j] + ls[j];
#pragma unroll
    for (int db = 0; db < 4; ++db)
#pragma unroll
      for (int j = 0; j < 4; ++j) acc_o[db][j] *= corr[j];

    // ---- P -> LDS (per-wave, swizzled rows of 128B); re-read as A-operand frags
#pragma unroll
    for (int kb = 0; kb < 4; ++kb)
#pragma unroll
      for (int j = 0; j < 4; ++j) {
        int row = hi4 * 4 + j, col = kb * 16 + lo;
        int off = row * 128 + ((col * 2) ^ ((row & 7) << 4));
        *reinterpret_cast<short*>((char*)pw + off) = f2bf(s[kb][j]);
      }
    __builtin_amdgcn_sched_barrier(0);   // keep P writes before P reads
    bf16x8 pa[2];
#pragma unroll
    for (int kk = 0; kk < 2; ++kk) {
      int off = lo * 128 + ((kk * 64 + hi4 * 16) ^ ((lo & 7) << 4));
      pa[kk] = *reinterpret_cast<const bf16x8*>((const char*)pw + off);
    }

    // ---- PV: B-operand = rows of V^T tile (same swizzled pattern as K reads)
#pragma unroll
    for (int db = 0; db < 4; ++db) {
#pragma unroll
      for (int kk = 0; kk < 2; ++kk) {
        int vrow = db * 16 + lo;
        int voff = vrow * 128 + ((kk * 64 + hi4 * 16) ^ ((lo & 7) << 4));
        bf16x8 v8 = *reinterpret_cast<const bf16x8*>((const char*)Vts + voff);
        acc_o[db] = mfma16(pa[kk], v8, acc_o[db]);
      }
    }
  }

  // ---- epilogue: O[b, m, h*64 + d] bf16
  const int b = bh >> 3, h = bh & 7;
#pragma unroll
  for (int j = 0; j < 4; ++j) {
    float inv = 1.0f / l_run[j];
    int mrow = q0 + wave * 16 + hi4 * 4 + j;
    size_t base = ((size_t)(b * 2048 + mrow)) * 512 + h * 64;
#pragma unroll
    for (int db = 0; db < 4; ++db)
      Og[base + db * 16 + lo] = f2bf(acc_o[db][j] * inv);
  }
}

// ---------------------------------------------------------------------------
extern "C" void kernel_launch(void* const* d_in, const int* in_sizes, int n_in,
                              void* d_out, int out_size, void* d_ws, size_t ws_size,
                              hipStream_t stream) {
  const float* x  = (const float*)d_in[0];
  const float* Wq = (const float*)d_in[1];
  const float* Wk = (const float*)d_in[2];
  const float* Wv = (const float*)d_in[3];
  const float* Wo = (const float*)d_in[4];
  const float* bo = (const float*)d_in[5];
  float* out = (float*)d_out;

  char* ws = (char*)d_ws;
  short* Wqk_hi = (short*)(ws);                           // [1024][512]
  short* Wqk_lo = (short*)(ws + (1 << 20));
  short* Wv_t   = (short*)(ws + (2 << 20));               // [512][512]
  short* Wo_t   = (short*)(ws + (2 << 20) + 512 * 512 * 2);
  char* big = ws + 3 * (1 << 20);
  const size_t SZ = (size_t)ROWS * 512 * 2;               // 16 MiB per tensor
  short* Qh = (short*)(big);
  short* Ql = (short*)(big + SZ);
  short* Kh = (short*)(big + 2 * SZ);
  short* Kl = (short*)(big + 3 * SZ);
  short* VT = (short*)(big + 4 * SZ);                     // [bh][d][m]
  short* Ob = (short*)(big + 5 * SZ);
  (void)in_sizes; (void)n_in; (void)out_size; (void)ws_size;

  prep_w<<<dim3(256), dim3(256), 0, stream>>>(Wq, Wk, Wv, Wo, Wqk_hi, Wqk_lo, Wv_t, Wo_t);
  gemm_kern<0><<<dim3(8, 128), dim3(256), 0, stream>>>(x, nullptr, Wqk_hi, Wqk_lo,
                                                       Qh, Ql, Kh, Kl, nullptr, nullptr);
  gemm_kern<1><<<dim3(4, 128), dim3(256), 0, stream>>>(x, nullptr, Wv_t, nullptr,
                                                       VT, nullptr, nullptr, nullptr, nullptr, nullptr);
  attn_kern<<<dim3(32, 64), dim3(256), 0, stream>>>(Qh, Ql, Kh, Kl, VT, Ob);
  gemm_kern<2><<<dim3(4, 128), dim3(256), 0, stream>>>(nullptr, Ob, Wo_t, nullptr,
                                                       nullptr, nullptr, nullptr, nullptr, out, bo);
}

// Round 4
// 402.160 us; speedup vs baseline: 1.3469x; 1.1535x over previous
//
#include <hip/hip_runtime.h>
#include <hip/hip_bf16.h>
#include <cstdint>

#define DI __device__ __forceinline__

typedef __attribute__((ext_vector_type(8))) short bf16x8;   // 8 bf16 (4 VGPR) MFMA A/B frag
typedef __attribute__((ext_vector_type(4))) short s16x4;
typedef __attribute__((ext_vector_type(4))) float f32x4;    // MFMA C/D frag
typedef __attribute__((ext_vector_type(2))) int   i32x2;

static constexpr int BATCH = 8, SEQ = 2048;
static constexpr int ROWS = BATCH * SEQ;    // 16384
// logits = (q.k) * sqrt(512); fold sqrt(512)*log2(e) into Wq so we can use exp2
static constexpr float SCALE_Q = (float)(22.627416997969522 * 1.4426950408889634);

DI short f2bf(float f) { __hip_bfloat16 h = __float2bfloat16(f); return *reinterpret_cast<short*>(&h); }
DI float bf2f(short s) { __hip_bfloat16 h; *reinterpret_cast<short*>(&h) = s; return __bfloat162float(h); }
DI unsigned pack2(float a, float b) {
  return (unsigned)(unsigned short)f2bf(a) | ((unsigned)(unsigned short)f2bf(b) << 16);
}

DI void gload_lds16(const void* gp, void* lp) {
  __builtin_amdgcn_global_load_lds(
      (__attribute__((address_space(1))) void*)const_cast<void*>(gp),
      (__attribute__((address_space(3))) void*)lp, 16, 0, 0);
}
DI f32x4 mfma16(bf16x8 a, bf16x8 b, f32x4 c) {
  return __builtin_amdgcn_mfma_f32_16x16x32_bf16(a, b, c, 0, 0, 0);
}

// ---------------------------------------------------------------------------
// prep: W [512k][512n] fp32 -> W^T [n][k] bf16 (hi/lo split for Wq,Wk; Wq scaled)
// grid: 4 mats * 64 tiles of 64x64
__global__ __launch_bounds__(256)
void prep_w(const float* __restrict__ Wq, const float* __restrict__ Wk,
            const float* __restrict__ Wv, const float* __restrict__ Wo,
            short* __restrict__ Wqk_hi, short* __restrict__ Wqk_lo,
            short* __restrict__ Wv_t, short* __restrict__ Wo_t)
{
  __shared__ float t[64][65];
  const int blk = blockIdx.x;
  const int mat = blk >> 6;
  const int tile = blk & 63;
  const int tn = (tile & 7) * 64;
  const int tk = (tile >> 3) * 64;
  const float* src = mat == 0 ? Wq : mat == 1 ? Wk : mat == 2 ? Wv : Wo;
  const float scale = (mat == 0) ? SCALE_Q : 1.0f;
  const int tid = threadIdx.x;
#pragma unroll
  for (int i = 0; i < 16; ++i) {
    int idx = i * 256 + tid;
    t[idx >> 6][idx & 63] = src[(size_t)(tk + (idx >> 6)) * 512 + tn + (idx & 63)];
  }
  __syncthreads();
#pragma unroll
  for (int i = 0; i < 16; ++i) {
    int idx = i * 256 + tid;
    int nn = idx >> 6, kk = idx & 63;
    float v = t[kk][nn] * scale;
    short hb = f2bf(v);
    size_t o = (size_t)(tn + nn) * 512 + (tk + kk);
    if (mat <= 1) {
      Wqk_hi[(size_t)mat * 512 * 512 + o] = hb;
      Wqk_lo[(size_t)mat * 512 * 512 + o] = f2bf(v - bf2f(hb));
    } else if (mat == 2) Wv_t[o] = hb;
    else Wo_t[o] = hb;
  }
}

// ---------------------------------------------------------------------------
// GEMM: C[16384 x N] = A[16384 x 512] * B^T[N x 512]
// MODE 0: A = x fp32 (split hi/lo), B split, N=1024 -> Q(hi/lo), K(hi/lo) as [bh][m][d]
// MODE 1: A = x fp32 (hi only),     B single, N=512 -> V^T as [bh][d][m]
// MODE 2: A = O bf16,               B single, N=512 -> out fp32 + bias
// 128x128 tile, BK=32, 4 waves (2x2), 16x16x32 bf16 MFMA.
// LDS rows are 64B = 4 chunks of 16B; chunk XOR-swizzled with ((row>>1)&3)
// (write-side permute == read-side permute, bijective) -> frag reads 2-way (free).
template<int MODE>
__global__ __launch_bounds__(256, 2)
void gemm_kern(const float* __restrict__ Axf, const short* __restrict__ Axb,
               const short* __restrict__ Bhg, const short* __restrict__ Blg,
               short* __restrict__ O0h, short* __restrict__ O0l,
               short* __restrict__ O1h, short* __restrict__ O1l,
               float* __restrict__ Of, const float* __restrict__ bias)
{
  constexpr bool SPLIT = (MODE == 0);
  __shared__ __align__(16) short Ah[128 * 32];
  __shared__ __align__(16) short Bh[128 * 32];
  __shared__ __align__(16) short Al[SPLIT ? 128 * 32 : 16];
  __shared__ __align__(16) short Bl[SPLIT ? 128 * 32 : 16];

  const int tid = threadIdx.x;
  const int wave = tid >> 6, lane = tid & 63, lo = lane & 15, hi4 = lane >> 4;
  const int wr = wave >> 1, wc = wave & 1;
  const int m0 = blockIdx.y * 128, n0 = blockIdx.x * 128;

  f32x4 acc[4][4] = {};

  for (int kt = 0; kt < 16; ++kt) {
    __syncthreads();   // previous iteration's LDS reads complete
    // ---- stage A (rows 64B; chunk c holds k = c*8..c*8+7, stored at chunk c^((row>>1)&3))
    if constexpr (MODE != 2) {
#pragma unroll
      for (int r2 = 0; r2 < 4; ++r2) {
        int idx = r2 * 256 + tid;
        int row = idx >> 3, c4 = idx & 7;
        const float4 v = *reinterpret_cast<const float4*>(Axf + (size_t)(m0 + row) * 512 + kt * 32 + c4 * 4);
        s16x4 h4, l4;
#pragma unroll
        for (int j = 0; j < 4; ++j) {
          float f = ((const float*)&v)[j];
          short hb = f2bf(f);
          h4[j] = hb;
          if constexpr (SPLIT) l4[j] = f2bf(f - bf2f(hb));
        }
        int off = row * 64 + ((((c4 >> 1) ^ ((row >> 1) & 3)) << 4) | ((c4 & 1) << 3));
        *reinterpret_cast<s16x4*>((char*)Ah + off) = h4;
        if constexpr (SPLIT) *reinterpret_cast<s16x4*>((char*)Al + off) = l4;
      }
    } else {
#pragma unroll
      for (int is = 0; is < 2; ++is) {
        int rowl = is * 64 + wave * 16 + (lane >> 2);
        int chunk = (lane & 3) ^ ((rowl >> 1) & 3);
        const char* src = (const char*)Axb + ((size_t)(m0 + rowl) * 512 + kt * 32) * 2 + chunk * 16;
        gload_lds16(src, (char*)Ah + is * 4096 + wave * 1024);
      }
    }
    // ---- stage B (global_load_lds; source chunk permuted so LDS lands swizzled)
#pragma unroll
    for (int is = 0; is < 2; ++is) {
      int rowl = is * 64 + wave * 16 + (lane >> 2);
      int chunk = (lane & 3) ^ ((rowl >> 1) & 3);
      size_t gb = ((size_t)(n0 + rowl) * 512 + kt * 32) * 2 + chunk * 16;
      gload_lds16((const char*)Bhg + gb, (char*)Bh + is * 4096 + wave * 1024);
      if constexpr (SPLIT)
        gload_lds16((const char*)Blg + gb, (char*)Bl + is * 4096 + wave * 1024);
    }
    __syncthreads();
    // ---- fragments (A row = lane&15, k-chunk hi4 read at slot hi4^((row>>1)&3))
    bf16x8 a_h[4], a_l[4], b_h[4], b_l[4];
#pragma unroll
    for (int m = 0; m < 4; ++m) {
      int ar = wr * 64 + m * 16 + lo;
      int off = ar * 64 + ((hi4 ^ ((ar >> 1) & 3)) << 4);
      a_h[m] = *reinterpret_cast<const bf16x8*>((const char*)Ah + off);
      if constexpr (SPLIT) a_l[m] = *reinterpret_cast<const bf16x8*>((const char*)Al + off);
    }
#pragma unroll
    for (int n = 0; n < 4; ++n) {
      int br = wc * 64 + n * 16 + lo;
      int off = br * 64 + ((hi4 ^ ((br >> 1) & 3)) << 4);
      b_h[n] = *reinterpret_cast<const bf16x8*>((const char*)Bh + off);
      if constexpr (SPLIT) b_l[n] = *reinterpret_cast<const bf16x8*>((const char*)Bl + off);
    }
#pragma unroll
    for (int m = 0; m < 4; ++m)
#pragma unroll
      for (int n = 0; n < 4; ++n) {
        acc[m][n] = mfma16(a_h[m], b_h[n], acc[m][n]);
        if constexpr (SPLIT) {
          acc[m][n] = mfma16(a_h[m], b_l[n], acc[m][n]);
          acc[m][n] = mfma16(a_l[m], b_h[n], acc[m][n]);
        }
      }
  }
  // ---- epilogue. D layout: col = lane&15, row = (lane>>4)*4 + j
#pragma unroll
  for (int m = 0; m < 4; ++m)
#pragma unroll
    for (int n = 0; n < 4; ++n) {
      if constexpr (MODE == 1) {
        // pack 4 consecutive m into one 8B store of V^T[bh][d][m]
        int cg = n0 + wc * 64 + n * 16 + lo;          // 0..511 = h*64+d
        int rgb = m0 + wr * 64 + m * 16 + hi4 * 4;    // j = 0..3 consecutive rows
        int bh = (rgb >> 11) * 8 + (cg >> 6);
        s16x4 vt4;
#pragma unroll
        for (int j = 0; j < 4; ++j) vt4[j] = f2bf(acc[m][n][j]);
        size_t o = ((size_t)(bh * 64 + (cg & 63))) * 2048 + (rgb & 2047);
        *reinterpret_cast<s16x4*>(O0h + o) = vt4;
      } else {
#pragma unroll
        for (int j = 0; j < 4; ++j) {
          int rg = m0 + wr * 64 + m * 16 + hi4 * 4 + j;
          int cg = n0 + wc * 64 + n * 16 + lo;
          float v = acc[m][n][j];
          if constexpr (MODE == 2) {
            Of[(size_t)rg * 512 + cg] = v + bias[cg];
          } else {
            int mat = cg >> 9;      // uniform per block
            int c9 = cg & 511;
            size_t o = ((size_t)((rg >> 11) * 8 + (c9 >> 6)) * 2048 + (rg & 2047)) * 64 + (c9 & 63);
            short hb = f2bf(v);
            short lb = f2bf(v - bf2f(hb));
            if (mat == 0) { O0h[o] = hb; O0l[o] = lb; }
            else          { O1h[o] = hb; O1l[o] = lb; }
          }
        }
      }
    }
}

// ---------------------------------------------------------------------------
// Flash attention. grid = (32 q-tiles, 64 bh). 4 waves x 16 q-rows, 64-key tiles.
// Q,K in bf16 hi/lo (3-product MFMA); V^T [bh][d][m] plain bf16.
// SWAPPED QK^T: S^T = mfma(K, Q) so each lane holds the 16 P-values of ONE
// q-row (q = lane&15, keys kb*16 + hi4*4 + j) -> in-lane softmax, 2-shfl
// reduces, b64 P writes. Defer-max (THR=8) skips rescale on most tiles.
// LDS rows 128B = 8 chunks of 16B, XOR-swizzled with ((row&7)<<4).
__global__ __launch_bounds__(256, 2)
void attn_kern(const short* __restrict__ Qh, const short* __restrict__ Ql,
               const short* __restrict__ Kh, const short* __restrict__ Kl,
               const short* __restrict__ VTg, short* __restrict__ Og)
{
  __shared__ __align__(16) short Ksh[64 * 64];
  __shared__ __align__(16) short Ksl[64 * 64];
  __shared__ __align__(16) short Vts[64 * 64];
  __shared__ __align__(16) short Ps[4][1024];

  const int bh = blockIdx.y, qt = blockIdx.x;
  const int tid = threadIdx.x, wave = tid >> 6, lane = tid & 63, lo = lane & 15, hi4 = lane >> 4;
  const int q0 = qt * 64;

  // Q fragments (row/col = lane&15, k = (lane>>4)*8 + j per 32-k MFMA)
  const size_t qoff = ((size_t)bh * 2048 + q0 + wave * 16 + lo) * 64;
  bf16x8 qh[2], ql[2];
#pragma unroll
  for (int kk = 0; kk < 2; ++kk) {
    qh[kk] = *reinterpret_cast<const bf16x8*>(Qh + qoff + kk * 32 + hi4 * 8);
    ql[kk] = *reinterpret_cast<const bf16x8*>(Ql + qoff + kk * 32 + hi4 * 8);
  }

  f32x4 acc_o[4] = {};
  float m_run = -3.0e38f, l_run = 0.f;

  short* pw = &Ps[wave][0];

  for (int kt = 0; kt < 32; ++kt) {
    __syncthreads();   // all waves done reading previous K/V tile
    // ---- stage K hi/lo rows [64 key][64 d] + V^T rows [64 d][64 key], swizzled src
#pragma unroll
    for (int is = 0; is < 2; ++is) {
      int rowl = is * 32 + wave * 8 + (lane >> 3);
      int chunk = (lane & 7) ^ (rowl & 7);
      size_t gbK = ((size_t)bh * 2048 + kt * 64 + rowl) * 128 + chunk * 16;   // bytes
      gload_lds16((const char*)Kh + gbK, (char*)Ksh + is * 4096 + wave * 1024);
      gload_lds16((const char*)Kl + gbK, (char*)Ksl + is * 4096 + wave * 1024);
      size_t gbV = (((size_t)bh * 64 + rowl) * 2048 + kt * 64) * 2 + chunk * 16;  // bytes
      gload_lds16((const char*)VTg + gbV, (char*)Vts + is * 4096 + wave * 1024);
    }
    __syncthreads();

    // ---- S^T = K Q^T (hh + hl + lh): D row = key (kb*16 + hi4*4 + j), col = q (lo)
    f32x4 s[4];
    __builtin_amdgcn_s_setprio(1);
#pragma unroll
    for (int kb = 0; kb < 4; ++kb) {
      f32x4 t = {0.f, 0.f, 0.f, 0.f};
#pragma unroll
      for (int kk = 0; kk < 2; ++kk) {
        int krow = kb * 16 + lo;
        int off = krow * 128 + ((kk * 64 + hi4 * 16) ^ ((krow & 7) << 4));
        bf16x8 kh8 = *reinterpret_cast<const bf16x8*>((const char*)Ksh + off);
        bf16x8 kl8 = *reinterpret_cast<const bf16x8*>((const char*)Ksl + off);
        t = mfma16(kh8, qh[kk], t);
        t = mfma16(kl8, qh[kk], t);
        t = mfma16(kh8, ql[kk], t);
      }
      s[kb] = t;
    }
    __builtin_amdgcn_s_setprio(0);

    // ---- in-lane online softmax for q-row = lo (16 keys per lane, 4 hi4 groups)
    float mt = s[0][0];
#pragma unroll
    for (int kb = 0; kb < 4; ++kb)
#pragma unroll
      for (int j = 0; j < 4; ++j) mt = fmaxf(mt, s[kb][j]);
    mt = fmaxf(mt, __shfl_xor(mt, 16));
    mt = fmaxf(mt, __shfl_xor(mt, 32));
    if (!__all(mt - m_run <= 8.0f)) {     // defer-max: rescale only on real growth
      float mn = fmaxf(m_run, mt);
      float corr = exp2f(m_run - mn);
      m_run = mn;
      l_run *= corr;
#pragma unroll
      for (int j = 0; j < 4; ++j) {
        float cj = __shfl(corr, hi4 * 4 + j);   // row-space broadcast
#pragma unroll
        for (int db = 0; db < 4; ++db) acc_o[db][j] *= cj;
      }
    }
    float ls = 0.f;
#pragma unroll
    for (int kb = 0; kb < 4; ++kb)
#pragma unroll
      for (int j = 0; j < 4; ++j) {
        float p = exp2f(s[kb][j] - m_run);
        s[kb][j] = p;
        ls += p;
      }
    ls += __shfl_xor(ls, 16);
    ls += __shfl_xor(ls, 32);
    l_run += ls;

    // ---- P^T rows -> LDS: lane writes keys kb*16+hi4*4..+3 of row q=lo (b64, swizzled)
#pragma unroll
    for (int kb = 0; kb < 4; ++kb) {
      i32x2 w;
      w.x = (int)pack2(s[kb][0], s[kb][1]);
      w.y = (int)pack2(s[kb][2], s[kb][3]);
      int off = lo * 128 + ((kb * 32 + hi4 * 8) ^ ((lo & 7) << 4));
      *reinterpret_cast<i32x2*>((char*)pw + off) = w;
    }
    __builtin_amdgcn_sched_barrier(0);   // keep P writes before P reads
    bf16x8 pa[2];
#pragma unroll
    for (int kk = 0; kk < 2; ++kk) {
      int off = lo * 128 + ((kk * 64 + hi4 * 16) ^ ((lo & 7) << 4));
      pa[kk] = *reinterpret_cast<const bf16x8*>((const char*)pw + off);
    }

    // ---- PV: B-operand = rows of V^T tile (same swizzled pattern as K reads)
    __builtin_amdgcn_s_setprio(1);
#pragma unroll
    for (int db = 0; db < 4; ++db) {
#pragma unroll
      for (int kk = 0; kk < 2; ++kk) {
        int vrow = db * 16 + lo;
        int voff = vrow * 128 + ((kk * 64 + hi4 * 16) ^ ((lo & 7) << 4));
        bf16x8 v8 = *reinterpret_cast<const bf16x8*>((const char*)Vts + voff);
        acc_o[db] = mfma16(pa[kk], v8, acc_o[db]);
      }
    }
    __builtin_amdgcn_s_setprio(0);
  }

  // ---- epilogue: O[b, m, h*64 + d] bf16 (l_run lives in lane-space, shfl to rows)
  const int b = bh >> 3, h = bh & 7;
#pragma unroll
  for (int j = 0; j < 4; ++j) {
    float lr = __shfl(l_run, hi4 * 4 + j);
    float inv = 1.0f / lr;
    int mrow = q0 + wave * 16 + hi4 * 4 + j;
    size_t base = ((size_t)(b * 2048 + mrow)) * 512 + h * 64;
#pragma unroll
    for (int db = 0; db < 4; ++db)
      Og[base + db * 16 + lo] = f2bf(acc_o[db][j] * inv);
  }
}

// ---------------------------------------------------------------------------
extern "C" void kernel_launch(void* const* d_in, const int* in_sizes, int n_in,
                              void* d_out, int out_size, void* d_ws, size_t ws_size,
                              hipStream_t stream) {
  const float* x  = (const float*)d_in[0];
  const float* Wq = (const float*)d_in[1];
  const float* Wk = (const float*)d_in[2];
  const float* Wv = (const float*)d_in[3];
  const float* Wo = (const float*)d_in[4];
  const float* bo = (const float*)d_in[5];
  float* out = (float*)d_out;

  char* ws = (char*)d_ws;
  short* Wqk_hi = (short*)(ws);                           // [1024][512]
  short* Wqk_lo = (short*)(ws + (1 << 20));
  short* Wv_t   = (short*)(ws + (2 << 20));               // [512][512]
  short* Wo_t   = (short*)(ws + (2 << 20) + 512 * 512 * 2);
  char* big = ws + 3 * (1 << 20);
  const size_t SZ = (size_t)ROWS * 512 * 2;               // 16 MiB per tensor
  short* Qh = (short*)(big);
  short* Ql = (short*)(big + SZ);
  short* Kh = (short*)(big + 2 * SZ);
  short* Kl = (short*)(big + 3 * SZ);
  short* VT = (short*)(big + 4 * SZ);                     // [bh][d][m]
  short* Ob = (short*)(big + 5 * SZ);
  (void)in_sizes; (void)n_in; (void)out_size; (void)ws_size;

  prep_w<<<dim3(256), dim3(256), 0, stream>>>(Wq, Wk, Wv, Wo, Wqk_hi, Wqk_lo, Wv_t, Wo_t);
  gemm_kern<0><<<dim3(8, 128), dim3(256), 0, stream>>>(x, nullptr, Wqk_hi, Wqk_lo,
                                                       Qh, Ql, Kh, Kl, nullptr, nullptr);
  gemm_kern<1><<<dim3(4, 128), dim3(256), 0, stream>>>(x, nullptr, Wv_t, nullptr,
                                                       VT, nullptr, nullptr, nullptr, nullptr, nullptr);
  attn_kern<<<dim3(32, 64), dim3(256), 0, stream>>>(Qh, Ql, Kh, Kl, VT, Ob);
  gemm_kern<2><<<dim3(4, 128), dim3(256), 0, stream>>>(nullptr, Ob, Wo_t, nullptr,
                                                       nullptr, nullptr, nullptr, nullptr, out, bo);
}